// Round 12
// baseline (83.999 us; speedup 1.0000x reference)
//
#include <hip/hip_runtime.h>
#include <cstdint>

typedef unsigned short u16;
typedef __bf16 bf16x8 __attribute__((ext_vector_type(8)));
typedef float f32x4 __attribute__((ext_vector_type(4)));
typedef u16 u16x4 __attribute__((ext_vector_type(4)));
typedef u16 u16x8 __attribute__((ext_vector_type(8)));

static __device__ __forceinline__ u16 f2bf(float f) {
  return __builtin_bit_cast(u16, (__bf16)f);
}
static __device__ __forceinline__ float fexp2(float x) {
  float r;
  asm("v_exp_f32 %0, %1" : "=v"(r) : "v"(x));   // bare 2^x, 1 instr; exact for |x|<8
  return r;
}

#define GLOAD16(gsrc, ldst) \
  __builtin_amdgcn_global_load_lds((const __attribute__((address_space(1))) void*)(gsrc), \
                                   (__attribute__((address_space(3))) void*)(ldst), 16, 0, 0)

// block-wide counted-vmcnt barrier pair (GEMM)
#define WAIT_BAR_VM(n) do { \
    __builtin_amdgcn_sched_barrier(0); \
    asm volatile("s_waitcnt vmcnt(" #n ")" ::: "memory"); \
    __builtin_amdgcn_s_barrier(); \
    __builtin_amdgcn_sched_barrier(0); \
  } while (0)
#define WAIT_BAR_LGKM() do { \
    __builtin_amdgcn_sched_barrier(0); \
    asm volatile("s_waitcnt lgkmcnt(0)" ::: "memory"); \
    __builtin_amdgcn_s_barrier(); \
    __builtin_amdgcn_sched_barrier(0); \
  } while (0)

// wave-local waits (attention: no barrier — wave-private LDS regions)
#define WV_VM(n) do { \
    __builtin_amdgcn_sched_barrier(0); \
    asm volatile("s_waitcnt vmcnt(" #n ")" ::: "memory"); \
    __builtin_amdgcn_sched_barrier(0); \
  } while (0)
#define WV_LGKM() do { \
    __builtin_amdgcn_sched_barrier(0); \
    asm volatile("s_waitcnt lgkmcnt(0)" ::: "memory"); \
    __builtin_amdgcn_sched_barrier(0); \
  } while (0)

// B=2, T=2048, D=1024, H=16, HD=64, 3D=3072, M=B*T=4096
// ws layout (bytes):
//   xbf  @ 0         : 4096*1024*2   = 8388608
//   Wt   @ 8388608   : 3072*1024*2   = 6291456
//   qkv  @ 14680064  : 4096*3072*2   = 25165824   (q columns pre-scaled by 0.125*log2e)
//   vT   @ 39845888  : 32*64*2048*2  = 8388608    (total 48234496)

// ---------------- kernel 1: x fp32->bf16 convert + W transpose (fused) ----------------
__global__ __launch_bounds__(256) void k_prep(const float* __restrict__ x,
                                              const float* __restrict__ W,
                                              u16* __restrict__ xbf,
                                              u16* __restrict__ Wt) {
  __shared__ __align__(16) u16 tile[64 * 72];
  int t = threadIdx.x;
  if (blockIdx.x < 2048) {
    int idx = blockIdx.x * 256 + t;                // 524288 threads * 8 elems
    const float4* xv = (const float4*)x;
    float4 a = xv[(size_t)idx * 2];
    float4 b = xv[(size_t)idx * 2 + 1];
    u16x8 o;
    o[0]=f2bf(a.x); o[1]=f2bf(a.y); o[2]=f2bf(a.z); o[3]=f2bf(a.w);
    o[4]=f2bf(b.x); o[5]=f2bf(b.y); o[6]=f2bf(b.z); o[7]=f2bf(b.w);
    *(u16x8*)(xbf + (size_t)idx * 8) = o;
    return;
  }
  int bid = blockIdx.x - 2048;
  int bk = bid & 15, bn = bid >> 4;                // 16 k-tiles x 48 n-tiles
  int k0 = bk * 64, n0 = bn * 64;
  #pragma unroll
  for (int r = 0; r < 4; r++) {
    int id = r * 256 + t;                          // 0..1023
    int kl = id >> 4;
    int c  = (id & 15) * 4;
    float4 v = *(const float4*)(W + (size_t)(k0 + kl) * 3072 + n0 + c);
    u16x4 o; o[0]=f2bf(v.x); o[1]=f2bf(v.y); o[2]=f2bf(v.z); o[3]=f2bf(v.w);
    *(u16x4*)(tile + kl * 72 + c) = o;
  }
  __syncthreads();
  #pragma unroll
  for (int r = 0; r < 2; r++) {
    int id = r * 256 + t;                          // 0..511
    int nl = id >> 3;
    int w  = id & 7;                               // 16B chunk = 8 k
    u16x8 o;
    #pragma unroll
    for (int i = 0; i < 8; i++) o[i] = tile[(w * 8 + i) * 72 + nl];
    *(u16x8*)(Wt + (size_t)(n0 + nl) * 1024 + k0 + w * 8) = o;
  }
}

// ------- kernel 2: qkv = xbf @ Wt^T + b  (bf16 MFMA, 128x192x64 tiles) -------
// 4 waves (2M x 2N), wave = 64x96 (acc 4x6). BK=64, double-buffered LDS with
// COUNTED-vmcnt sync. 128B LDS rows, 8-unit XOR swizzle u ^= row&7.
// 512 blocks = 2/CU. q cols pre-scaled by 0.125*log2e; v cols dual-written
// transposed into vT[b][h][d][t].
__global__ __launch_bounds__(256, 2) void k_gemm_qkv(const u16* __restrict__ xbf,
                                                     const u16* __restrict__ wt,
                                                     const float* __restrict__ bias,
                                                     u16* __restrict__ qkv,
                                                     u16* __restrict__ vT) {
  __shared__ __align__(16) u16 As[2 * 128 * 64];   // 32 KB (2 bufs x 16KB)
  __shared__ __align__(16) u16 Bs[2 * 192 * 64];   // 48 KB (2 bufs x 24KB)
  int wg = blockIdx.x;
  int swz = (wg & 7) * 64 + (wg >> 3);             // XCD-aware, bijective (512 = 8*64)
  int mt = swz >> 4, nt = swz & 15;                // 32 m-tiles x 16 n-tiles
  int m0 = mt * 128, n0 = nt * 192;
  int t = threadIdx.x;                             // 0..255
  int lane = t & 63, wid = t >> 6;
  int wm = wid >> 1, wn = wid & 1;
  int g = lane >> 4, li = lane & 15;

  f32x4 acc[4][6];
  #pragma unroll
  for (int i = 0; i < 4; i++)
    #pragma unroll
    for (int j = 0; j < 6; j++) acc[i][j] = (f32x4){0.f, 0.f, 0.f, 0.f};

  // staging: 128B rows = 8 units; phys unit w holds global unit w^(row&7)
  auto stage = [&](int kt, int buf) {
    char* ad = (char*)As + buf * 16384;
    char* bd = (char*)Bs + buf * 24576;
    #pragma unroll
    for (int i = 0; i < 4; i++) {
      int p = t + i * 256;                         // A: 128 rows x 8 units = 1024
      int row = p >> 3, ug = (p & 7) ^ (row & 7);
      GLOAD16(xbf + (size_t)(m0 + row) * 1024 + kt * 64 + ug * 8, ad + p * 16);
    }
    #pragma unroll
    for (int i = 0; i < 6; i++) {
      int p = t + i * 256;                         // B: 192 rows x 8 units = 1536
      int row = p >> 3, ug = (p & 7) ^ (row & 7);
      GLOAD16(wt + (size_t)(n0 + row) * 1024 + kt * 64 + ug * 8, bd + p * 16);
    }
  };

  stage(0, 0);
  for (int kt = 0; kt < 16; ++kt) {
    if (kt < 15) {
      stage(kt + 1, (kt & 1) ^ 1);                 // 10 loads stay in flight
      WAIT_BAR_VM(10);                             // tile-kt landed (all waves)
    } else {
      WAIT_BAR_VM(0);
    }
    const char* ab = (const char*)As + (kt & 1) * 16384;
    const char* bb = (const char*)Bs + (kt & 1) * 24576;

    #pragma unroll
    for (int kk = 0; kk < 2; ++kk) {               // two K=32 halves of the 128B row
      bf16x8 af[4], bfr[6];
      #pragma unroll
      for (int mi = 0; mi < 4; mi++) {
        int row = wm * 64 + mi * 16 + li;
        int u = (kk * 4 + g) ^ (row & 7);
        af[mi] = *(const bf16x8*)(ab + row * 128 + u * 16);
      }
      #pragma unroll
      for (int ni = 0; ni < 6; ni++) {
        int row = wn * 96 + ni * 16 + li;
        int u = (kk * 4 + g) ^ (row & 7);
        bfr[ni] = *(const bf16x8*)(bb + row * 128 + u * 16);
      }
      __builtin_amdgcn_s_setprio(1);
      #pragma unroll
      for (int mi = 0; mi < 4; mi++)
        #pragma unroll
        for (int ni = 0; ni < 6; ni++)
          acc[mi][ni] = __builtin_amdgcn_mfma_f32_16x16x32_bf16(af[mi], bfr[ni], acc[mi][ni], 0, 0, 0);
      __builtin_amdgcn_s_setprio(0);
    }

    WAIT_BAR_LGKM();                               // reads done; buf free for kt+2
  }

  // epilogue: +bias, scale q-cols, ->bf16; q/k cols -> qkv; v cols -> vT transposed
  int b = m0 >> 11;              // batch (M-tile never crosses batch: 2048%128==0)
  int tbase = m0 & 2047;
  #pragma unroll
  for (int ni = 0; ni < 6; ni++) {
    int col = n0 + wn * 96 + ni * 16 + li;
    float bv = bias[col];
    float sc = (col < 1024) ? 0.18033688011112042f : 1.0f;  // 0.125*log2(e) on q
    #pragma unroll
    for (int mi = 0; mi < 4; mi++) {
      int trow = tbase + wm * 64 + mi * 16 + g * 4;
      if (col < 2048) {
        #pragma unroll
        for (int j = 0; j < 4; j++) {
          float v = (acc[mi][ni][j] + bv) * sc;
          qkv[(size_t)(b * 2048 + trow + j) * 3072 + col] = f2bf(v);
        }
      } else {
        u16x4 o;
        #pragma unroll
        for (int j = 0; j < 4; j++) o[j] = f2bf(acc[mi][ni][j] + bv);
        // vT[b][h][d][t] with h*64+d = col-2048; 4 consecutive t
        *(u16x4*)(vT + ((size_t)(b * 1024 + (col - 2048))) * 2048 + trow) = o;
      }
    }
  }
}

// ------- kernel 3: flash attention, barrier-free wave-private streaming -------
// Block = 2 waves x 64 q (128 thr); wave w streams key-half w (1024 keys =
// 16 phases x 64 keys) with WAVE-PRIVATE K/V LDS (16 KB each, single-buffered)
// staged via global_load_lds and ordered purely by per-wave vmcnt/lgkmcnt —
// ZERO barriers in the main loop. Grid 1024, 32 KB LDS -> 4 independent
// free-running blocks/CU: MFMA/VALU/LDS overlap across desynced waves (m114).
// Steady state: 16 DMAs in flight; vmcnt(8) @phase-top = K landed, vmcnt(8)
// pre-PV = V landed (in-order retire). QK in 2 st-batches (exp interleaved,
// halves S liveness). lsum on VALU tree (+2 epilogue shuffles) — MFMA is the
// binding pipe. kperm64/pack/PV-read layout verbatim from the proven R8 kernel.
// In-LDS combine of the two key-half partials (static softmax: ADD).
__global__ __launch_bounds__(128, 2) void k_attn(const u16* __restrict__ qkv,
                                                 const u16* __restrict__ vT,
                                                 float* __restrict__ out) {
  __shared__ __align__(16) u16 smem[16384];        // 32 KB: wave0 [0,16K), wave1 [16K,32K)
  int bid = blockIdx.x;
  int bh = bid & 31, qt = bid >> 5;                // 32 bh x 32 q-tiles (64 q)
  int b = bh >> 4, h = bh & 15;
  int qbase = qt * 64;
  int t = threadIdx.x, lane = t & 63, wave = t >> 6;  // wave = key-half
  int g = lane >> 4, li = lane & 15;

  // Q fragments: 4 x 16 q-rows x 2 k-chunks (pre-scaled by 0.125*log2e)
  bf16x8 q[4][2];
  #pragma unroll
  for (int qf = 0; qf < 4; qf++) {
    size_t qrow = (size_t)(b * 2048 + qbase + qf * 16 + li) * 3072 + h * 64;
    q[qf][0] = *(const bf16x8*)(qkv + qrow + g * 8);
    q[qf][1] = *(const bf16x8*)(qkv + qrow + 32 + g * 8);
  }

  f32x4 o[4][4];                                   // O^T accum: [qf][dt]
  #pragma unroll
  for (int i = 0; i < 4; i++)
    #pragma unroll
    for (int j = 0; j < 4; j++) o[i][j] = (f32x4){0.f, 0.f, 0.f, 0.f};
  float la[4] = {0.f, 0.f, 0.f, 0.f};

  // key-half folded into bases
  const u16* kbase_g = qkv + (size_t)(b * 2048 + wave * 1024) * 3072 + 1024 + h * 64;
  const u16* vbase_g = vT + (size_t)(bh * 64) * 2048 + wave * 1024;

  // wave-private staging: K 64 rows x 128B, V 64 d-rows x 128B; per lane 8+8
  // GLOAD16. p = lane + i*64 -> row = (lane>>3) + 8i, unit = lane&7 (const).
  // kperm64(r) = (r&32) | ((r&16)>>2) | (((r>>2)&3)<<3) | (r&3)  [R8, proven]
  int r0 = lane >> 3, uu = lane & 7;
  int kuo = (uu ^ (r0 & 7)) * 8;                   // const per lane (r&7 invariant in i)
  int kR[8];
  #pragma unroll
  for (int i = 0; i < 8; i++) {
    int r = r0 + 8 * i;
    kR[i] = (r & 32) | ((r & 16) >> 2) | (((r >> 2) & 3) << 3) | (r & 3);
  }
  size_t vS0 = (size_t)r0 * 2048 + kuo;            // d = r0 + 8i; same XOR (d&7 inv.)
  char* kd = (char*)smem + wave * 16384;
  char* vd = kd + 8192;

  auto stageK = [&](int key0) {
    #pragma unroll
    for (int i = 0; i < 8; i++)
      GLOAD16(kbase_g + (size_t)(key0 + kR[i]) * 3072 + kuo, kd + (lane + i * 64) * 16);
  };
  auto stageV = [&](int key0) {
    #pragma unroll
    for (int i = 0; i < 8; i++)
      GLOAD16(vbase_g + vS0 + (size_t)i * 16384 + key0, vd + (lane + i * 64) * 16);
  };

  stageK(0);
  stageV(0);
  WV_VM(0);                                        // drain (incl. Q loads); wave-local

  int u0 = g ^ (li & 7);

  #pragma unroll 1
  for (int ph = 0; ph < 16; ++ph) {
    if (ph > 0) WV_VM(8);                          // K(ph) landed (8 oldest retire)

    // QK in 2 st-batches; exp/pack interleaved between MFMA clusters
    bf16x8 pb[4][2];
    #pragma unroll
    for (int b2 = 0; b2 < 2; ++b2) {
      f32x4 s[2][4];
      __builtin_amdgcn_s_setprio(1);
      #pragma unroll
      for (int st = 0; st < 2; ++st) {
        int row = (b2 * 2 + st) * 16 + li;
        bf16x8 kf0 = *(const bf16x8*)(kd + row * 128 + u0 * 16);
        bf16x8 kf1 = *(const bf16x8*)(kd + row * 128 + (u0 ^ 4) * 16);
        #pragma unroll
        for (int qf = 0; qf < 4; qf++) {
          f32x4 z = (f32x4){0.f, 0.f, 0.f, 0.f};
          s[st][qf] = __builtin_amdgcn_mfma_f32_16x16x32_bf16(kf0, q[qf][0], z, 0, 0, 0);
          s[st][qf] = __builtin_amdgcn_mfma_f32_16x16x32_bf16(kf1, q[qf][1], s[st][qf], 0, 0, 0);
        }
      }
      __builtin_amdgcn_s_setprio(0);
      #pragma unroll
      for (int qf = 0; qf < 4; qf++) {
        float p8[8];
        #pragma unroll
        for (int e = 0; e < 8; e++) p8[e] = fexp2(s[e >> 2][qf][e & 3]);
        la[qf] += ((p8[0] + p8[1]) + (p8[2] + p8[3])) + ((p8[4] + p8[5]) + (p8[6] + p8[7]));
        #pragma unroll
        for (int e = 0; e < 8; e++) pb[qf][b2][e] = (__bf16)p8[e];
      }
    }

    WV_LGKM();                                     // K ds_reads in regs
    if (ph < 15) stageK((ph + 1) * 64);            // 8 loads into my K buf

    if (ph < 15) WV_VM(8); else WV_VM(0);          // V(ph) landed

    __builtin_amdgcn_s_setprio(1);
    #pragma unroll
    for (int c = 0; c < 2; c++) {
      #pragma unroll
      for (int dt = 0; dt < 4; dt++) {
        int d = dt * 16 + li;
        bf16x8 vf = *(const bf16x8*)(vd + d * 128 + (((c * 4 + g) ^ (d & 7)) << 4));
        #pragma unroll
        for (int qf = 0; qf < 4; qf++)
          o[qf][dt] = __builtin_amdgcn_mfma_f32_16x16x32_bf16(vf, pb[qf][c], o[qf][dt], 0, 0, 0);
      }
    }
    __builtin_amdgcn_s_setprio(0);

    WV_LGKM();                                     // V ds_reads in regs
    if (ph < 15) stageV((ph + 1) * 64);            // 8 loads into my V buf
  }

  // wave-local lsum: combine the 4 g-groups (each lane holds 16 key-slots of q=li)
  #pragma unroll
  for (int qf = 0; qf < 4; qf++) {
    la[qf] += __shfl_xor(la[qf], 16);
    la[qf] += __shfl_xor(la[qf], 32);
  }

  // ---- in-LDS K-split combine (static softmax: partials ADD) ----
  float* pO = (float*)smem;                        // [64 q][64 d] f32, unit-swizzled
  float* pL = (float*)((char*)smem + 16384);       // [64] f32 lsum (wave 1)
  __syncthreads();
  if (wave) {
    #pragma unroll
    for (int qf = 0; qf < 4; qf++) {
      int qq = qf * 16 + li;
      #pragma unroll
      for (int dt = 0; dt < 4; dt++) {
        int u = dt * 4 + g;
        *(f32x4*)((char*)pO + qq * 256 + ((u ^ (qq & 7)) << 4)) = o[qf][dt];
      }
      if (g == 0) pL[qq] = la[qf];
    }
  }
  __syncthreads();
  if (!wave) {
    #pragma unroll
    for (int qf = 0; qf < 4; qf++) {
      int qq = qf * 16 + li;
      float inv = 1.0f / (la[qf] + pL[qq]);
      size_t orow = (size_t)(b * 2048 + qbase + qq) * 1024 + h * 64;
      #pragma unroll
      for (int dt = 0; dt < 4; dt++) {
        int u = dt * 4 + g;
        f32x4 p2 = *(const f32x4*)((const char*)pO + qq * 256 + ((u ^ (qq & 7)) << 4));
        f32x4 r = (o[qf][dt] + p2) * inv;
        *(f32x4*)(out + orow + u * 4) = r;         // 16B store
      }
    }
  }
}

extern "C" void kernel_launch(void* const* d_in, const int* in_sizes, int n_in,
                              void* d_out, int out_size, void* d_ws, size_t ws_size,
                              hipStream_t stream) {
  const float* x    = (const float*)d_in[0];
  const float* W    = (const float*)d_in[1];
  const float* bias = (const float*)d_in[2];
  float* out = (float*)d_out;
  char* ws = (char*)d_ws;
  u16* xbf = (u16*)(ws + 0);
  u16* wt  = (u16*)(ws + 8388608);
  u16* qkv = (u16*)(ws + 14680064);
  u16* vt  = (u16*)(ws + 39845888);

  k_prep<<<2816, 256, 0, stream>>>(x, W, xbf, wt);
  k_gemm_qkv<<<512, 256, 0, stream>>>(xbf, wt, bias, qkv, vt);
  k_attn<<<1024, 128, 0, stream>>>(qkv, vt, out);
}